// Round 4
// baseline (375.553 us; speedup 1.0000x reference)
//
#include <hip/hip_runtime.h>
#include <hip/hip_bf16.h>
#include <math.h>

#define N_NODES 4096
#define FDIM 512
#define D 64
#define H 8
#define NWORDS (N_NODES / 64)   // 64 u64 words per adjacency row

typedef __attribute__((ext_vector_type(8))) short bf16x8;   // 8 bf16 = 4 VGPRs
typedef __attribute__((ext_vector_type(4))) float f32x4;

__device__ inline short f2bf(float x) {
    return (short)((__builtin_bit_cast(unsigned int, x) + 0x8000u) >> 16);
}

// ---------------------------------------------------------------- adj -> bitmask
__global__ void k_bits(const int* __restrict__ adj, unsigned long long* __restrict__ bits) {
    int idx = blockIdx.x * 256 + threadIdx.x;
    unsigned long long m = __ballot(adj[idx] != 0);
    if ((threadIdx.x & 63) == 0) bits[idx >> 6] = m;
}

// ---------------------------------------------------------------- GEMM  [N,512] @ [512,64] per head
__global__ void k_gemm(const float* __restrict__ X, const float* __restrict__ Wt,
                       float* __restrict__ Out, short* __restrict__ WBout) {
    const int h  = blockIdx.y;
    const int i0 = blockIdx.x * 64;
    const float* __restrict__ Wp   = Wt + (size_t)h * FDIM * D;
    float* __restrict__       outp = Out + (size_t)h * N_NODES * D;
    short* __restrict__       wbp  = WBout + (size_t)h * (N_NODES / 8) * D * 8;
    __shared__ float xs[64][33];
    __shared__ float ws[32][64];
    const int t  = threadIdx.x;
    const int tr = t >> 4, tc = t & 15;
    float acc[4][4] = {{0.f}};
    for (int kt = 0; kt < FDIM; kt += 32) {
        {
            const int r = t >> 3, kk = (t & 7) << 2;
            float4 a = *(const float4*)&X[(size_t)(i0 + r) * FDIM + kt + kk];
            xs[r][kk] = a.x; xs[r][kk + 1] = a.y; xs[r][kk + 2] = a.z; xs[r][kk + 3] = a.w;
            float4 b = *(const float4*)&X[(size_t)(i0 + r + 32) * FDIM + kt + kk];
            xs[r + 32][kk] = b.x; xs[r + 32][kk + 1] = b.y; xs[r + 32][kk + 2] = b.z; xs[r + 32][kk + 3] = b.w;
            const int kw = t >> 4, c = (t & 15) << 2;
            *(float4*)&ws[kw][c]      = *(const float4*)&Wp[(size_t)(kt + kw) * D + c];
            *(float4*)&ws[kw + 16][c] = *(const float4*)&Wp[(size_t)(kt + kw + 16) * D + c];
        }
        __syncthreads();
        #pragma unroll
        for (int k = 0; k < 32; ++k) {
            float w4[4];
            *(float4*)&w4[0] = *(float4*)&ws[k][tc << 2];
            float xv[4];
            #pragma unroll
            for (int rr = 0; rr < 4; ++rr) xv[rr] = xs[tr * 4 + rr][k];
            #pragma unroll
            for (int rr = 0; rr < 4; ++rr)
                #pragma unroll
                for (int cc = 0; cc < 4; ++cc) acc[rr][cc] += xv[rr] * w4[cc];
        }
        __syncthreads();
    }
    #pragma unroll
    for (int rr = 0; rr < 4; ++rr) {
        const int j = i0 + tr * 4 + rr;
        float4 v = make_float4(acc[rr][0], acc[rr][1], acc[rr][2], acc[rr][3]);
        *(float4*)&outp[(size_t)j * D + (tc << 2)] = v;
        const int jb = j >> 3, jo = j & 7;
        #pragma unroll
        for (int cc = 0; cc < 4; ++cc)
            wbp[((size_t)jb * D + (tc * 4 + cc)) * 8 + jo] = f2bf(acc[rr][cc]);
    }
}

// ---------------------------------------------------------------- f = Wh . a   (one wave per row)
__global__ void k_f(const float* __restrict__ Whp, const float* __restrict__ asrc,
                    const float* __restrict__ adst, float* __restrict__ fs,
                    float* __restrict__ fd) {
    const int h    = blockIdx.y;
    const int n    = blockIdx.x * 4 + (threadIdx.x >> 6);
    const int lane = threadIdx.x & 63;
    float v  = Whp[((size_t)h * N_NODES + n) * D + lane];
    float s1 = v * asrc[h * D + lane];
    float s2 = v * adst[h * D + lane];
    #pragma unroll
    for (int off = 32; off > 0; off >>= 1) {
        s1 += __shfl_down(s1, off);
        s2 += __shfl_down(s2, off);
    }
    if (lane == 0) {
        fs[(size_t)h * N_NODES + n] = s1;
        fd[(size_t)h * N_NODES + n] = s2;
    }
}

// ---------------------------------------------------------------- global max of fd per head
__global__ void k_gmax(const float* __restrict__ fd, float* __restrict__ gmax) {
    const int h = blockIdx.x;
    const int t = threadIdx.x;
    float m = -INFINITY;
    #pragma unroll
    for (int i = 0; i < 4; ++i) m = fmaxf(m, fd[(size_t)h * N_NODES + t + i * 1024]);
    #pragma unroll
    for (int off = 32; off > 0; off >>= 1) m = fmaxf(m, __shfl_xor(m, off));
    __shared__ float red[16];
    if ((t & 63) == 0) red[t >> 6] = m;
    __syncthreads();
    if (t == 0) {
        float r = red[0];
        #pragma unroll
        for (int i = 1; i < 16; ++i) r = fmaxf(r, red[i]);
        gmax[h] = r;
    }
}

// ---------------------------------------------------------------- column mean of Wh per head
__global__ void k_colmean(const float* __restrict__ Wh, float* __restrict__ colmean) {
    const int h  = blockIdx.y;
    const int i0 = blockIdx.x * 256;
    const int t  = threadIdx.x;
    const int d  = t & 63, rg = t >> 6;
    const float* __restrict__ base = Wh + (size_t)h * N_NODES * D;
    float s = 0.f;
    #pragma unroll 8
    for (int r = rg; r < 256; r += 4) s += base[(size_t)(i0 + r) * D + d];
    __shared__ float cs[4][64];
    cs[rg][d] = s;
    __syncthreads();
    if (t < 64)
        atomicAdd(&colmean[h * D + t],
                  (cs[0][t] + cs[1][t] + cs[2][t] + cs[3][t]) * (1.f / (float)N_NODES));
}

// ---------------------------------------------------------------- exp precompute (factored softmax)
// Per i: Ppos=exp(fs-m), Pneg=exp(0.2fs-m), T=exp(-fs); per j: Ed=exp(fd), Ed2=exp(0.2fd).
// m_i = leaky(fs_i + gmax) bounds leaky(fs_i+fd_j) for all j (leaky monotone).
__global__ void k_prep(const float* __restrict__ fs, const float* __restrict__ fd,
                       const float* __restrict__ gmax,
                       float* __restrict__ Ppos, float* __restrict__ Pneg,
                       float* __restrict__ T, float* __restrict__ Ed,
                       float* __restrict__ Ed2) {
    const int h = blockIdx.y;
    const size_t o = (size_t)h * N_NODES + blockIdx.x * 256 + threadIdx.x;
    const float fsv = fs[o], fdv = fd[o], gm = gmax[h];
    const float em = fsv + gm;
    const float m  = fmaxf(em, 0.2f * em);
    Ppos[o] = __expf(fsv - m);
    Pneg[o] = __expf(0.2f * fsv - m);
    T[o]    = __expf(-fsv);
    Ed[o]   = __expf(fdv);
    Ed2[o]  = __expf(0.2f * fdv);
}

// ---------------------------------------------------------------- MFMA attention aggregation (j-split)
// grid (N/64, Hcnt, JS). Writes RAW numerator slab + denominator slab (exact partials, shared m_i).
// No exp in the loop: p = bit * (Ed_j > T_i ? Ed_j*Ppos_i : Ed2_j*Pneg_i).
__global__ void __launch_bounds__(256) k_accum(
    const unsigned int* __restrict__ bits32,
    const short* __restrict__ WB,
    const float* __restrict__ Pposb, const float* __restrict__ Pnegb,
    const float* __restrict__ Tb, const float* __restrict__ Edb,
    const float* __restrict__ Ed2b,
    float* __restrict__ num, float* __restrict__ den) {
    const int h    = blockIdx.y;
    const int i0   = blockIdx.x * 64;
    const int slab = blockIdx.z;
    const int kslab = N_NODES / gridDim.z;
    const int t    = threadIdx.x;
    const int w    = t >> 6;
    const int lane = t & 63;
    const int li   = lane & 15;
    const int quad = lane >> 4;
    const int k0   = quad * 8;

    const int    i_row = i0 + w * 16 + li;
    const size_t ho    = (size_t)h * N_NODES;
    const float  Pp    = Pposb[ho + i_row];
    const float  Pn    = Pnegb[ho + i_row];
    const float  Tv    = Tb[ho + i_row];
    const float* __restrict__ Ed  = Edb + ho;
    const float* __restrict__ Ed2 = Ed2b + ho;
    const short* __restrict__ Bh  = WB + (size_t)h * (N_NODES / 8) * D * 8;
    const unsigned int* __restrict__ brow = bits32 + (size_t)i_row * (NWORDS * 2);

    f32x4 c0 = {0.f, 0.f, 0.f, 0.f}, c1 = c0, c2 = c0, c3 = c0, c5 = c0;
    bf16x8 ones;
    #pragma unroll
    for (int j = 0; j < 8; ++j) ones[j] = (short)0x3F80;   // bf16 1.0

    const int k_beg = slab * kslab, k_end = k_beg + kslab;
    #pragma unroll 2
    for (int kt = k_beg; kt < k_end; kt += 32) {
        const float4 e0 = *(const float4*)&Ed[kt + k0];
        const float4 e1 = *(const float4*)&Ed[kt + k0 + 4];
        const float4 g0 = *(const float4*)&Ed2[kt + k0];
        const float4 g1 = *(const float4*)&Ed2[kt + k0 + 4];
        const unsigned int byte = (brow[kt >> 5] >> k0) & 0xFFu;
        float ev[8], gv[8];
        ev[0] = e0.x; ev[1] = e0.y; ev[2] = e0.z; ev[3] = e0.w;
        ev[4] = e1.x; ev[5] = e1.y; ev[6] = e1.z; ev[7] = e1.w;
        gv[0] = g0.x; gv[1] = g0.y; gv[2] = g0.z; gv[3] = g0.w;
        gv[4] = g1.x; gv[5] = g1.y; gv[6] = g1.z; gv[7] = g1.w;
        bf16x8 a;
        #pragma unroll
        for (int j = 0; j < 8; ++j) {
            const bool pos = ev[j] > Tv;            // <=> fs_i + fd_j > 0
            float p = pos ? ev[j] * Pp : gv[j] * Pn;
            p = ((byte >> j) & 1u) ? p : 0.f;
            a[j] = f2bf(p);
        }
        const short* bb = Bh + (size_t)((kt >> 3) + quad) * (D * 8) + li * 8;
        bf16x8 b0 = *(const bf16x8*)(bb);
        bf16x8 b1 = *(const bf16x8*)(bb + 128);
        bf16x8 b2 = *(const bf16x8*)(bb + 256);
        bf16x8 b3 = *(const bf16x8*)(bb + 384);
        c0 = __builtin_amdgcn_mfma_f32_16x16x32_bf16(a, b0, c0, 0, 0, 0);
        c1 = __builtin_amdgcn_mfma_f32_16x16x32_bf16(a, b1, c1, 0, 0, 0);
        c2 = __builtin_amdgcn_mfma_f32_16x16x32_bf16(a, b2, c2, 0, 0, 0);
        c3 = __builtin_amdgcn_mfma_f32_16x16x32_bf16(a, b3, c3, 0, 0, 0);
        c5 = __builtin_amdgcn_mfma_f32_16x16x32_bf16(a, ones, c5, 0, 0, 0);
    }

    // raw slab writes; C/D layout col=lane&15, row=quad*4+reg
    const size_t so = (size_t)(slab * gridDim.y + h);
    float tiles[4][4];
    #pragma unroll
    for (int r = 0; r < 4; ++r) { tiles[0][r] = c0[r]; tiles[1][r] = c1[r]; tiles[2][r] = c2[r]; tiles[3][r] = c3[r]; }
    #pragma unroll
    for (int t4 = 0; t4 < 4; ++t4)
        #pragma unroll
        for (int r = 0; r < 4; ++r) {
            const int row = i0 + w * 16 + quad * 4 + r;
            num[(so * N_NODES + row) * D + t4 * 16 + li] = tiles[t4][r];
        }
    if (li == 0)
        #pragma unroll
        for (int r = 0; r < 4; ++r)
            den[so * N_NODES + i0 + w * 16 + quad * 4 + r] = c5[r];
}

// ---------------------------------------------------------------- layer-1 combine (JS=2): norm+fallback+ELU
__global__ void k_post1(const float* __restrict__ num, const float* __restrict__ den,
                        const float* __restrict__ colmean, float* __restrict__ hcat) {
    const int h   = blockIdx.y;
    const int i0  = blockIdx.x * 64;
    const int t   = threadIdx.x;
    const int row = i0 + (t >> 2);
    const int cb  = (t & 3) * 16;
    const size_t HN = (size_t)gridDim.y * N_NODES;
    const size_t r0 = (size_t)h * N_NODES + row;
    const float dsum = den[r0] + den[HN + r0];
    const bool  uni  = !(dsum > 0.f);
    const float linv = uni ? 0.f : 1.f / dsum;
    #pragma unroll
    for (int c = 0; c < 4; ++c) {
        const int col = cb + c * 4;
        float4 a = *(const float4*)&num[r0 * D + col];
        float4 b = *(const float4*)&num[(HN + r0) * D + col];
        float4 v;
        v.x = (a.x + b.x) * linv; v.y = (a.y + b.y) * linv;
        v.z = (a.z + b.z) * linv; v.w = (a.w + b.w) * linv;
        if (uni) v = *(const float4*)&colmean[h * D + col];
        v.x = v.x > 0.f ? v.x : __expf(v.x) - 1.f;
        v.y = v.y > 0.f ? v.y : __expf(v.y) - 1.f;
        v.z = v.z > 0.f ? v.z : __expf(v.z) - 1.f;
        v.w = v.w > 0.f ? v.w : __expf(v.w) - 1.f;
        *(float4*)&hcat[(size_t)row * (H * D) + h * D + col] = v;
    }
}

// ---------------------------------------------------------------- layer-2 combine (JS=8) + ELU + log_softmax
__global__ void k_lsm(const float* __restrict__ num, const float* __restrict__ den,
                      const float* __restrict__ cm, float* __restrict__ out) {
    const int n    = blockIdx.x * 4 + (threadIdx.x >> 6);
    const int lane = threadIdx.x & 63;
    float v = 0.f, ds = 0.f;
    #pragma unroll
    for (int s = 0; s < 8; ++s) v  += num[((size_t)s * N_NODES + n) * D + lane];
    #pragma unroll
    for (int s = 0; s < 8; ++s) ds += den[(size_t)s * N_NODES + n];
    v = (ds > 0.f) ? v / ds : cm[lane];
    v = v > 0.f ? v : __expf(v) - 1.f;
    float mx = v;
    #pragma unroll
    for (int off = 32; off > 0; off >>= 1) mx = fmaxf(mx, __shfl_xor(mx, off));
    float ex = __expf(v - mx);
    float sum = ex;
    #pragma unroll
    for (int off = 32; off > 0; off >>= 1) sum += __shfl_xor(sum, off);
    out[(size_t)n * D + lane] = (v - mx) - __logf(sum);
}

// ----------------------------------------------------------------
extern "C" void kernel_launch(void* const* d_in, const int* in_sizes, int n_in,
                              void* d_out, int out_size, void* d_ws, size_t ws_size,
                              hipStream_t stream) {
    const float* x      = (const float*)d_in[0];
    const int*   adj    = (const int*)d_in[1];
    const float* W      = (const float*)d_in[2];
    const float* a_src  = (const float*)d_in[3];
    const float* a_dst  = (const float*)d_in[4];
    const float* W_o    = (const float*)d_in[5];
    const float* ao_src = (const float*)d_in[6];
    const float* ao_dst = (const float*)d_in[7];
    float* out = (float*)d_out;

    char* wsp = (char*)d_ws;
    size_t off = 0;
    auto alloc = [&](size_t bytes) -> void* {
        void* p = wsp + off;
        off += (bytes + 255) & ~(size_t)255;
        return p;
    };
    unsigned long long* adj_bits = (unsigned long long*)alloc((size_t)N_NODES * NWORDS * 8);
    float* Wh    = (float*)alloc((size_t)H * N_NODES * D * 4);
    short* WhB   = (short*)alloc((size_t)H * N_NODES * D * 2);
    float* fs1   = (float*)alloc((size_t)H * N_NODES * 4);
    float* fd1   = (float*)alloc((size_t)H * N_NODES * 4);
    float* gmax1 = (float*)alloc((size_t)H * 4);
    float* cm1   = (float*)alloc((size_t)H * D * 4);
    float* Pp1   = (float*)alloc((size_t)H * N_NODES * 4);
    float* Pn1   = (float*)alloc((size_t)H * N_NODES * 4);
    float* T1    = (float*)alloc((size_t)H * N_NODES * 4);
    float* Ed1   = (float*)alloc((size_t)H * N_NODES * 4);
    float* Ee1   = (float*)alloc((size_t)H * N_NODES * 4);
    float* num1  = (float*)alloc((size_t)2 * H * N_NODES * D * 4);
    float* den1  = (float*)alloc((size_t)2 * H * N_NODES * 4);
    float* hcat  = (float*)alloc((size_t)N_NODES * H * D * 4);
    float* Who   = (float*)alloc((size_t)N_NODES * D * 4);
    short* WhoB  = (short*)alloc((size_t)N_NODES * D * 2);
    float* fs2   = (float*)alloc((size_t)N_NODES * 4);
    float* fd2   = (float*)alloc((size_t)N_NODES * 4);
    float* gmax2 = (float*)alloc(4);
    float* cm2   = (float*)alloc((size_t)D * 4);
    float* Pp2   = (float*)alloc((size_t)N_NODES * 4);
    float* Pn2   = (float*)alloc((size_t)N_NODES * 4);
    float* T2    = (float*)alloc((size_t)N_NODES * 4);
    float* Ed2   = (float*)alloc((size_t)N_NODES * 4);
    float* Ee2   = (float*)alloc((size_t)N_NODES * 4);
    float* num2  = (float*)alloc((size_t)8 * N_NODES * D * 4);
    float* den2  = (float*)alloc((size_t)8 * N_NODES * 4);

    const unsigned int* bits32 = (const unsigned int*)adj_bits;

    hipMemsetAsync(cm1, 0, (size_t)H * D * 4, stream);
    hipMemsetAsync(cm2, 0, (size_t)D * 4, stream);

    k_bits<<<dim3(N_NODES * N_NODES / 256), dim3(256), 0, stream>>>(adj, adj_bits);

    // layer 1 (8 heads, concat + ELU)
    k_gemm   <<<dim3(N_NODES / 64, H), dim3(256), 0, stream>>>(x, W, Wh, WhB);
    k_f      <<<dim3(N_NODES / 4, H),  dim3(256), 0, stream>>>(Wh, a_src, a_dst, fs1, fd1);
    k_gmax   <<<dim3(H), dim3(1024), 0, stream>>>(fd1, gmax1);
    k_colmean<<<dim3(16, H), dim3(256), 0, stream>>>(Wh, cm1);
    k_prep   <<<dim3(N_NODES / 256, H), dim3(256), 0, stream>>>(fs1, fd1, gmax1, Pp1, Pn1, T1, Ed1, Ee1);
    k_accum  <<<dim3(N_NODES / 64, H, 2), dim3(256), 0, stream>>>(bits32, WhB, Pp1, Pn1, T1, Ed1, Ee1,
                                                                  num1, den1);
    k_post1  <<<dim3(N_NODES / 64, H), dim3(256), 0, stream>>>(num1, den1, cm1, hcat);

    // layer 2 (single output head)
    k_gemm   <<<dim3(N_NODES / 64, 1), dim3(256), 0, stream>>>(hcat, W_o, Who, WhoB);
    k_f      <<<dim3(N_NODES / 4, 1),  dim3(256), 0, stream>>>(Who, ao_src, ao_dst, fs2, fd2);
    k_gmax   <<<dim3(1), dim3(1024), 0, stream>>>(fd2, gmax2);
    k_colmean<<<dim3(16, 1), dim3(256), 0, stream>>>(Who, cm2);
    k_prep   <<<dim3(N_NODES / 256, 1), dim3(256), 0, stream>>>(fs2, fd2, gmax2, Pp2, Pn2, T2, Ed2, Ee2);
    k_accum  <<<dim3(N_NODES / 64, 1, 8), dim3(256), 0, stream>>>(bits32, WhoB, Pp2, Pn2, T2, Ed2, Ee2,
                                                                  num2, den2);
    k_lsm    <<<dim3(N_NODES / 4), dim3(256), 0, stream>>>(num2, den2, cm2, out);
}

// Round 5
// 297.229 us; speedup vs baseline: 1.2635x; 1.2635x over previous
//
#include <hip/hip_runtime.h>
#include <hip/hip_bf16.h>
#include <math.h>

#define N_NODES 4096
#define FDIM 512            // K of both GEMMs (F_in = H*D = 512)
#define D 64
#define H 8
#define NWORDS (N_NODES / 64)

typedef __attribute__((ext_vector_type(8))) short bf16x8;   // 8 bf16 = 4 VGPRs
typedef __attribute__((ext_vector_type(4))) float f32x4;

__device__ inline short f2bf(float x) {                     // RNE
    return (short)((__builtin_bit_cast(unsigned int, x) + 0x8000u) >> 16);
}

// ---------------------------------------------------------------- adj -> bitmask
__global__ void k_bits(const int* __restrict__ adj, unsigned long long* __restrict__ bits) {
    int idx = blockIdx.x * 256 + threadIdx.x;
    unsigned long long m = __ballot(adj[idx] != 0);
    if ((threadIdx.x & 63) == 0) bits[idx >> 6] = m;
}

// ---------------------------------------------------------------- W [Hn,512,64] fp32 -> B-frag bf16
// frag layout per head: [(k>>3)][d][k&7]
__global__ void k_wfrag(const float* __restrict__ Wsrc, short* __restrict__ WF) {
    const size_t idx = (size_t)blockIdx.x * 256 + threadIdx.x;   // (h*512+k)*64+d
    const int d = idx & 63;
    const int k = (int)(idx >> 6) & 511;
    const int h = (int)(idx >> 15);
    WF[(((size_t)h * 64 + (k >> 3)) * 64 + d) * 8 + (k & 7)] = f2bf(Wsrc[idx]);
}

// ---------------------------------------------------------------- MFMA GEMM [N,512]@[512,64] per head
// Also writes bf16 frag copy of C and fused fs/fd = C.av / C.bv row dot-products.
__global__ void __launch_bounds__(256) k_gemm(
    const float* __restrict__ X,      // [N,512] (shared across heads)
    const short* __restrict__ WF,     // [Hn][64][64][8] bf16 frags
    const float* __restrict__ av,     // [Hn,64]
    const float* __restrict__ bv,     // [Hn,64]
    float* __restrict__ Out,          // [Hn,N,64]
    short* __restrict__ WBout,        // [Hn][N/8][64][8]
    float* __restrict__ fs, float* __restrict__ fd) {  // [Hn,N]
    const int h  = blockIdx.y;
    const int i0 = blockIdx.x * 64;
    const int t = threadIdx.x, w = t >> 6, lane = t & 63;
    const int li = lane & 15, quad = lane >> 4, k0 = quad * 8;
    const int row_a = i0 + w * 16 + li;
    const float* __restrict__ Xr  = X + (size_t)row_a * FDIM;
    const short* __restrict__ WFh = WF + (size_t)h * 64 * D * 8;

    f32x4 c0 = {0.f, 0.f, 0.f, 0.f}, c1 = c0, c2 = c0, c3 = c0;
    #pragma unroll 4
    for (int kt = 0; kt < FDIM; kt += 32) {
        float4 x0 = *(const float4*)&Xr[kt + k0];
        float4 x1 = *(const float4*)&Xr[kt + k0 + 4];
        bf16x8 a;
        a[0] = f2bf(x0.x); a[1] = f2bf(x0.y); a[2] = f2bf(x0.z); a[3] = f2bf(x0.w);
        a[4] = f2bf(x1.x); a[5] = f2bf(x1.y); a[6] = f2bf(x1.z); a[7] = f2bf(x1.w);
        const short* bb = WFh + (size_t)((kt >> 3) + quad) * (D * 8) + li * 8;
        bf16x8 b0 = *(const bf16x8*)(bb);
        bf16x8 b1 = *(const bf16x8*)(bb + 128);
        bf16x8 b2 = *(const bf16x8*)(bb + 256);
        bf16x8 b3 = *(const bf16x8*)(bb + 384);
        c0 = __builtin_amdgcn_mfma_f32_16x16x32_bf16(a, b0, c0, 0, 0, 0);
        c1 = __builtin_amdgcn_mfma_f32_16x16x32_bf16(a, b1, c1, 0, 0, 0);
        c2 = __builtin_amdgcn_mfma_f32_16x16x32_bf16(a, b2, c2, 0, 0, 0);
        c3 = __builtin_amdgcn_mfma_f32_16x16x32_bf16(a, b3, c3, 0, 0, 0);
    }
    float av4[4], bv4[4];
    #pragma unroll
    for (int t4 = 0; t4 < 4; ++t4) {
        av4[t4] = av[h * D + t4 * 16 + li];
        bv4[t4] = bv[h * D + t4 * 16 + li];
    }
    float tiles[4][4];
    #pragma unroll
    for (int r = 0; r < 4; ++r) { tiles[0][r] = c0[r]; tiles[1][r] = c1[r]; tiles[2][r] = c2[r]; tiles[3][r] = c3[r]; }
    #pragma unroll
    for (int r = 0; r < 4; ++r) {
        const int row = i0 + w * 16 + quad * 4 + r;
        float pa = 0.f, pb = 0.f;
        #pragma unroll
        for (int t4 = 0; t4 < 4; ++t4) {
            const float v = tiles[t4][r];
            const int d = t4 * 16 + li;
            Out[((size_t)h * N_NODES + row) * D + d] = v;
            WBout[((size_t)h * (N_NODES / 8) + (row >> 3)) * (D * 8) + d * 8 + (row & 7)] = f2bf(v);
            pa += v * av4[t4];
            pb += v * bv4[t4];
        }
        #pragma unroll
        for (int off = 1; off < 16; off <<= 1) {
            pa += __shfl_xor(pa, off);
            pb += __shfl_xor(pb, off);
        }
        if (li == 0) {
            fs[(size_t)h * N_NODES + row] = pa;
            fd[(size_t)h * N_NODES + row] = pb;
        }
    }
}

// ---------------------------------------------------------------- global max of fd per head
__global__ void k_gmax(const float* __restrict__ fd, float* __restrict__ gmax) {
    const int h = blockIdx.x;
    const int t = threadIdx.x;
    float m = -INFINITY;
    #pragma unroll
    for (int i = 0; i < 4; ++i) m = fmaxf(m, fd[(size_t)h * N_NODES + t + i * 1024]);
    #pragma unroll
    for (int off = 32; off > 0; off >>= 1) m = fmaxf(m, __shfl_xor(m, off));
    __shared__ float red[16];
    if ((t & 63) == 0) red[t >> 6] = m;
    __syncthreads();
    if (t == 0) {
        float r = red[0];
        #pragma unroll
        for (int i = 1; i < 16; ++i) r = fmaxf(r, red[i]);
        gmax[h] = r;
    }
}

// ---------------------------------------------------------------- column mean of Wh per head
__global__ void k_colmean(const float* __restrict__ Wh, float* __restrict__ colmean) {
    const int h  = blockIdx.y;
    const int i0 = blockIdx.x * 256;
    const int t  = threadIdx.x;
    const int d  = t & 63, rg = t >> 6;
    const float* __restrict__ base = Wh + (size_t)h * N_NODES * D;
    float s = 0.f;
    #pragma unroll 8
    for (int r = rg; r < 256; r += 4) s += base[(size_t)(i0 + r) * D + d];
    __shared__ float cs[4][64];
    cs[rg][d] = s;
    __syncthreads();
    if (t < 64)
        atomicAdd(&colmean[h * D + t],
                  (cs[0][t] + cs[1][t] + cs[2][t] + cs[3][t]) * (1.f / (float)N_NODES));
}

// ---------------------------------------------------------------- exp precompute (factored softmax)
__global__ void k_prep(const float* __restrict__ fs, const float* __restrict__ fd,
                       const float* __restrict__ gmax,
                       float* __restrict__ Ppos, float* __restrict__ Pneg,
                       float* __restrict__ T, float* __restrict__ Ed,
                       float* __restrict__ Ed2) {
    const int h = blockIdx.y;
    const size_t o = (size_t)h * N_NODES + blockIdx.x * 256 + threadIdx.x;
    const float fsv = fs[o], fdv = fd[o], gm = gmax[h];
    const float em = fsv + gm;
    const float m  = fmaxf(em, 0.2f * em);
    Ppos[o] = __expf(fsv - m);
    Pneg[o] = __expf(0.2f * fsv - m);
    T[o]    = __expf(-fsv);
    Ed[o]   = __expf(fdv);
    Ed2[o]  = __expf(0.2f * fdv);
}

// ---------------------------------------------------------------- MFMA attention aggregation (j-split)
// Software-pipelined: next step's loads issued before current step's compute.
// p = bit * (Ed_j > T_i ? Ed_j*Ppos_i : Ed2_j*Pneg_i); masked via sign-extend AND on fp32 bits;
// bf16 by truncation, packed pairwise with v_perm_b32.
__global__ void __launch_bounds__(256) k_accum(
    const unsigned int* __restrict__ bits32,
    const short* __restrict__ WB,
    const float* __restrict__ Pposb, const float* __restrict__ Pnegb,
    const float* __restrict__ Tb, const float* __restrict__ Edb,
    const float* __restrict__ Ed2b,
    float* __restrict__ num, float* __restrict__ den, int kslab) {
    const int h    = blockIdx.y;
    const int i0   = blockIdx.x * 64;
    const int slab = blockIdx.z;
    const int t = threadIdx.x, w = t >> 6, lane = t & 63;
    const int li = lane & 15, quad = lane >> 4, k0 = quad * 8;

    const int    i_row = i0 + w * 16 + li;
    const size_t ho    = (size_t)h * N_NODES;
    const float  Pp    = Pposb[ho + i_row];
    const float  Pn    = Pnegb[ho + i_row];
    const float  Tv    = Tb[ho + i_row];
    const float* __restrict__ Ed  = Edb + ho;
    const float* __restrict__ Ed2 = Ed2b + ho;
    const short* __restrict__ Bh  = WB + (size_t)h * (N_NODES / 8) * D * 8;
    const unsigned int* __restrict__ brow = bits32 + (size_t)i_row * (NWORDS * 2);

    f32x4 c0 = {0.f, 0.f, 0.f, 0.f}, c1 = c0, c2 = c0, c3 = c0, c5 = c0;
    bf16x8 ones;
    #pragma unroll
    for (int j = 0; j < 8; ++j) ones[j] = (short)0x3F80;

    const int k_beg = slab * kslab, k_end = k_beg + kslab;

    // current-step registers
    float4 e0, e1, g0, g1; unsigned int byt; bf16x8 b0, b1, b2, b3;
    {
        const int kt = k_beg;
        e0 = *(const float4*)&Ed[kt + k0];  e1 = *(const float4*)&Ed[kt + k0 + 4];
        g0 = *(const float4*)&Ed2[kt + k0]; g1 = *(const float4*)&Ed2[kt + k0 + 4];
        byt = (brow[kt >> 5] >> k0) & 0xFFu;
        const short* bb = Bh + (size_t)((kt >> 3) + quad) * (D * 8) + li * 8;
        b0 = *(const bf16x8*)(bb);       b1 = *(const bf16x8*)(bb + 128);
        b2 = *(const bf16x8*)(bb + 256); b3 = *(const bf16x8*)(bb + 384);
    }
    for (int kt = k_beg; kt < k_end; kt += 32) {
        // prefetch next step (wrap to k_beg on last iter; harmless re-load)
        const int kn = (kt + 32 < k_end) ? kt + 32 : k_beg;
        float4 ne0 = *(const float4*)&Ed[kn + k0];
        float4 ne1 = *(const float4*)&Ed[kn + k0 + 4];
        float4 ng0 = *(const float4*)&Ed2[kn + k0];
        float4 ng1 = *(const float4*)&Ed2[kn + k0 + 4];
        unsigned int nbyt = (brow[kn >> 5] >> k0) & 0xFFu;
        const short* nbb = Bh + (size_t)((kn >> 3) + quad) * (D * 8) + li * 8;
        bf16x8 nb0 = *(const bf16x8*)(nbb);
        bf16x8 nb1 = *(const bf16x8*)(nbb + 128);
        bf16x8 nb2 = *(const bf16x8*)(nbb + 256);
        bf16x8 nb3 = *(const bf16x8*)(nbb + 384);

        float ev[8], gv[8];
        ev[0] = e0.x; ev[1] = e0.y; ev[2] = e0.z; ev[3] = e0.w;
        ev[4] = e1.x; ev[5] = e1.y; ev[6] = e1.z; ev[7] = e1.w;
        gv[0] = g0.x; gv[1] = g0.y; gv[2] = g0.z; gv[3] = g0.w;
        gv[4] = g1.x; gv[5] = g1.y; gv[6] = g1.z; gv[7] = g1.w;
        unsigned int pa[8];
        #pragma unroll
        for (int j = 0; j < 8; ++j) {
            const bool pos = ev[j] > Tv;
            const float val = pos ? ev[j] : gv[j];
            const float fac = pos ? Pp : Pn;
            const float p   = val * fac;
            const int   msk = ((int)(byt << (31 - j))) >> 31;   // all-ones iff bit j set
            pa[j] = __builtin_bit_cast(unsigned int, p) & (unsigned int)msk;
        }
        bf16x8 a;
        unsigned int* au = (unsigned int*)&a;
        au[0] = __builtin_amdgcn_perm(pa[1], pa[0], 0x07060302);
        au[1] = __builtin_amdgcn_perm(pa[3], pa[2], 0x07060302);
        au[2] = __builtin_amdgcn_perm(pa[5], pa[4], 0x07060302);
        au[3] = __builtin_amdgcn_perm(pa[7], pa[6], 0x07060302);

        c0 = __builtin_amdgcn_mfma_f32_16x16x32_bf16(a, b0, c0, 0, 0, 0);
        c1 = __builtin_amdgcn_mfma_f32_16x16x32_bf16(a, b1, c1, 0, 0, 0);
        c2 = __builtin_amdgcn_mfma_f32_16x16x32_bf16(a, b2, c2, 0, 0, 0);
        c3 = __builtin_amdgcn_mfma_f32_16x16x32_bf16(a, b3, c3, 0, 0, 0);
        c5 = __builtin_amdgcn_mfma_f32_16x16x32_bf16(a, ones, c5, 0, 0, 0);

        e0 = ne0; e1 = ne1; g0 = ng0; g1 = ng1; byt = nbyt;
        b0 = nb0; b1 = nb1; b2 = nb2; b3 = nb3;
    }

    const size_t so = (size_t)(slab * gridDim.y + h);
    float tiles[4][4];
    #pragma unroll
    for (int r = 0; r < 4; ++r) { tiles[0][r] = c0[r]; tiles[1][r] = c1[r]; tiles[2][r] = c2[r]; tiles[3][r] = c3[r]; }
    #pragma unroll
    for (int t4 = 0; t4 < 4; ++t4)
        #pragma unroll
        for (int r = 0; r < 4; ++r) {
            const int row = i0 + w * 16 + quad * 4 + r;
            num[(so * N_NODES + row) * D + t4 * 16 + li] = tiles[t4][r];
        }
    if (li == 0)
        #pragma unroll
        for (int r = 0; r < 4; ++r)
            den[so * N_NODES + i0 + w * 16 + quad * 4 + r] = c5[r];
}

// ---------------------------------------------------------------- layer-1 combine (JS=2): norm+fallback+ELU
__global__ void k_post1(const float* __restrict__ num, const float* __restrict__ den,
                        const float* __restrict__ colmean, float* __restrict__ hcat) {
    const int h   = blockIdx.y;
    const int i0  = blockIdx.x * 64;
    const int t   = threadIdx.x;
    const int row = i0 + (t >> 2);
    const int cb  = (t & 3) * 16;
    const size_t HN = (size_t)gridDim.y * N_NODES;
    const size_t r0 = (size_t)h * N_NODES + row;
    const float dsum = den[r0] + den[HN + r0];
    const bool  uni  = !(dsum > 0.f);
    const float linv = uni ? 0.f : 1.f / dsum;
    #pragma unroll
    for (int c = 0; c < 4; ++c) {
        const int col = cb + c * 4;
        float4 a = *(const float4*)&num[r0 * D + col];
        float4 b = *(const float4*)&num[(HN + r0) * D + col];
        float4 v;
        v.x = (a.x + b.x) * linv; v.y = (a.y + b.y) * linv;
        v.z = (a.z + b.z) * linv; v.w = (a.w + b.w) * linv;
        if (uni) v = *(const float4*)&colmean[h * D + col];
        v.x = v.x > 0.f ? v.x : __expf(v.x) - 1.f;
        v.y = v.y > 0.f ? v.y : __expf(v.y) - 1.f;
        v.z = v.z > 0.f ? v.z : __expf(v.z) - 1.f;
        v.w = v.w > 0.f ? v.w : __expf(v.w) - 1.f;
        *(float4*)&hcat[(size_t)row * (H * D) + h * D + col] = v;
    }
}

// ---------------------------------------------------------------- layer-2 combine (JS=8) + ELU + log_softmax
__global__ void k_lsm(const float* __restrict__ num, const float* __restrict__ den,
                      const float* __restrict__ cm, float* __restrict__ out) {
    const int n    = blockIdx.x * 4 + (threadIdx.x >> 6);
    const int lane = threadIdx.x & 63;
    float v = 0.f, ds = 0.f;
    #pragma unroll
    for (int s = 0; s < 8; ++s) v  += num[((size_t)s * N_NODES + n) * D + lane];
    #pragma unroll
    for (int s = 0; s < 8; ++s) ds += den[(size_t)s * N_NODES + n];
    v = (ds > 0.f) ? v / ds : cm[lane];
    v = v > 0.f ? v : __expf(v) - 1.f;
    float mx = v;
    #pragma unroll
    for (int off = 32; off > 0; off >>= 1) mx = fmaxf(mx, __shfl_xor(mx, off));
    float ex = __expf(v - mx);
    float sum = ex;
    #pragma unroll
    for (int off = 32; off > 0; off >>= 1) sum += __shfl_xor(sum, off);
    out[(size_t)n * D + lane] = (v - mx) - __logf(sum);
}

// ----------------------------------------------------------------
extern "C" void kernel_launch(void* const* d_in, const int* in_sizes, int n_in,
                              void* d_out, int out_size, void* d_ws, size_t ws_size,
                              hipStream_t stream) {
    const float* x      = (const float*)d_in[0];
    const int*   adj    = (const int*)d_in[1];
    const float* W      = (const float*)d_in[2];
    const float* a_src  = (const float*)d_in[3];
    const float* a_dst  = (const float*)d_in[4];
    const float* W_o    = (const float*)d_in[5];
    const float* ao_src = (const float*)d_in[6];
    const float* ao_dst = (const float*)d_in[7];
    float* out = (float*)d_out;

    char* wsp = (char*)d_ws;
    size_t off = 0;
    auto alloc = [&](size_t bytes) -> void* {
        void* p = wsp + off;
        off += (bytes + 255) & ~(size_t)255;
        return p;
    };
    unsigned long long* adj_bits = (unsigned long long*)alloc((size_t)N_NODES * NWORDS * 8);
    short* WF1   = (short*)alloc((size_t)H * 64 * D * 8 * 2);
    short* WoF   = (short*)alloc((size_t)64 * D * 8 * 2);
    float* Wh    = (float*)alloc((size_t)H * N_NODES * D * 4);
    short* WhB   = (short*)alloc((size_t)H * N_NODES * D * 2);
    float* fs1   = (float*)alloc((size_t)H * N_NODES * 4);
    float* fd1   = (float*)alloc((size_t)H * N_NODES * 4);
    float* gmax1 = (float*)alloc((size_t)H * 4);
    float* cm1   = (float*)alloc((size_t)H * D * 4);
    float* Pp1   = (float*)alloc((size_t)H * N_NODES * 4);
    float* Pn1   = (float*)alloc((size_t)H * N_NODES * 4);
    float* T1    = (float*)alloc((size_t)H * N_NODES * 4);
    float* Ed1   = (float*)alloc((size_t)H * N_NODES * 4);
    float* Ee1   = (float*)alloc((size_t)H * N_NODES * 4);
    float* num1  = (float*)alloc((size_t)2 * H * N_NODES * D * 4);
    float* den1  = (float*)alloc((size_t)2 * H * N_NODES * 4);
    float* hcat  = (float*)alloc((size_t)N_NODES * H * D * 4);
    float* Who   = (float*)alloc((size_t)N_NODES * D * 4);
    short* WhoB  = (short*)alloc((size_t)N_NODES * D * 2);
    float* fs2   = (float*)alloc((size_t)N_NODES * 4);
    float* fd2   = (float*)alloc((size_t)N_NODES * 4);
    float* gmax2 = (float*)alloc(4);
    float* cm2   = (float*)alloc((size_t)D * 4);
    float* Pp2   = (float*)alloc((size_t)N_NODES * 4);
    float* Pn2   = (float*)alloc((size_t)N_NODES * 4);
    float* T2    = (float*)alloc((size_t)N_NODES * 4);
    float* Ed2   = (float*)alloc((size_t)N_NODES * 4);
    float* Ee2   = (float*)alloc((size_t)N_NODES * 4);
    float* num2  = (float*)alloc((size_t)8 * N_NODES * D * 4);
    float* den2  = (float*)alloc((size_t)8 * N_NODES * 4);

    const unsigned int* bits32 = (const unsigned int*)adj_bits;

    hipMemsetAsync(cm1, 0, (size_t)H * D * 4, stream);
    hipMemsetAsync(cm2, 0, (size_t)D * 4, stream);

    k_bits <<<dim3(N_NODES * N_NODES / 256), dim3(256), 0, stream>>>(adj, adj_bits);
    k_wfrag<<<dim3(H * FDIM * D / 256), dim3(256), 0, stream>>>(W, WF1);
    k_wfrag<<<dim3(FDIM * D / 256), dim3(256), 0, stream>>>(W_o, WoF);

    // layer 1 (8 heads, concat + ELU)
    k_gemm   <<<dim3(N_NODES / 64, H), dim3(256), 0, stream>>>(x, WF1, a_src, a_dst,
                                                               Wh, WhB, fs1, fd1);
    k_gmax   <<<dim3(H), dim3(1024), 0, stream>>>(fd1, gmax1);
    k_colmean<<<dim3(16, H), dim3(256), 0, stream>>>(Wh, cm1);
    k_prep   <<<dim3(N_NODES / 256, H), dim3(256), 0, stream>>>(fs1, fd1, gmax1, Pp1, Pn1, T1, Ed1, Ee1);
    k_accum  <<<dim3(N_NODES / 64, H, 2), dim3(256), 0, stream>>>(bits32, WhB, Pp1, Pn1, T1, Ed1, Ee1,
                                                                  num1, den1, N_NODES / 2);
    k_post1  <<<dim3(N_NODES / 64, H), dim3(256), 0, stream>>>(num1, den1, cm1, hcat);

    // layer 2 (single output head)
    k_gemm   <<<dim3(N_NODES / 64, 1), dim3(256), 0, stream>>>(hcat, WoF, ao_src, ao_dst,
                                                               Who, WhoB, fs2, fd2);
    k_gmax   <<<dim3(1), dim3(1024), 0, stream>>>(fd2, gmax2);
    k_colmean<<<dim3(16, 1), dim3(256), 0, stream>>>(Who, cm2);
    k_prep   <<<dim3(N_NODES / 256, 1), dim3(256), 0, stream>>>(fs2, fd2, gmax2, Pp2, Pn2, T2, Ed2, Ee2);
    k_accum  <<<dim3(N_NODES / 64, 1, 8), dim3(256), 0, stream>>>(bits32, WhoB, Pp2, Pn2, T2, Ed2, Ee2,
                                                                  num2, den2, N_NODES / 8);
    k_lsm    <<<dim3(N_NODES / 4), dim3(256), 0, stream>>>(num2, den2, cm2, out);
}

// Round 6
// 255.304 us; speedup vs baseline: 1.4710x; 1.1642x over previous
//
#include <hip/hip_runtime.h>
#include <hip/hip_bf16.h>
#include <math.h>

#define N_NODES 4096
#define FDIM 512            // K of both GEMMs (F_in = H*D = 512)
#define D 64
#define H 8
#define NWORDS (N_NODES / 64)

typedef __attribute__((ext_vector_type(8))) short bf16x8;   // 8 bf16 = 4 VGPRs
typedef __attribute__((ext_vector_type(4))) float f32x4;

__device__ inline short f2bf(float x) {                     // RNE
    return (short)((__builtin_bit_cast(unsigned int, x) + 0x8000u) >> 16);
}

// async global->LDS 16B copy (DMA, no VGPR round-trip). LDS dst must be
// wave-uniform base + lane*16 — caller guarantees lane-contiguous layout.
__device__ inline void gl2lds16(const void* g, void* l) {
#if defined(__has_builtin) && __has_builtin(__builtin_amdgcn_global_load_lds)
    __builtin_amdgcn_global_load_lds(
        (const __attribute__((address_space(1))) unsigned int*)g,
        (__attribute__((address_space(3))) unsigned int*)l, 16, 0, 0);
#else
    *(uint4*)l = *(const uint4*)g;
#endif
}

// ---------------------------------------------------------------- adj -> bitmask
__global__ void k_bits(const int* __restrict__ adj, unsigned long long* __restrict__ bits) {
    int idx = blockIdx.x * 256 + threadIdx.x;
    unsigned long long m = __ballot(adj[idx] != 0);
    if ((threadIdx.x & 63) == 0) bits[idx >> 6] = m;
}

// ---------------------------------------------------------------- W [Hn,512,64] fp32 -> B-frag bf16
__global__ void k_wfrag(const float* __restrict__ Wsrc, short* __restrict__ WF) {
    const size_t idx = (size_t)blockIdx.x * 256 + threadIdx.x;   // (h*512+k)*64+d
    const int d = idx & 63;
    const int k = (int)(idx >> 6) & 511;
    const int h = (int)(idx >> 15);
    WF[(((size_t)h * 64 + (k >> 3)) * 64 + d) * 8 + (k & 7)] = f2bf(Wsrc[idx]);
}

// ---------------------------------------------------------------- MFMA GEMM [N,512]@[512,64] per head
// Also writes bf16 frag copy of C and fused fs/fd = C.av / C.bv row dot-products.
__global__ void __launch_bounds__(256) k_gemm(
    const float* __restrict__ X, const short* __restrict__ WF,
    const float* __restrict__ av, const float* __restrict__ bv,
    float* __restrict__ Out, short* __restrict__ WBout,
    float* __restrict__ fs, float* __restrict__ fd) {
    const int h  = blockIdx.y;
    const int i0 = blockIdx.x * 64;
    const int t = threadIdx.x, w = t >> 6, lane = t & 63;
    const int li = lane & 15, quad = lane >> 4, k0 = quad * 8;
    const int row_a = i0 + w * 16 + li;
    const float* __restrict__ Xr  = X + (size_t)row_a * FDIM;
    const short* __restrict__ WFh = WF + (size_t)h * 64 * D * 8;

    f32x4 c0 = {0.f, 0.f, 0.f, 0.f}, c1 = c0, c2 = c0, c3 = c0;
    #pragma unroll 4
    for (int kt = 0; kt < FDIM; kt += 32) {
        float4 x0 = *(const float4*)&Xr[kt + k0];
        float4 x1 = *(const float4*)&Xr[kt + k0 + 4];
        bf16x8 a;
        a[0] = f2bf(x0.x); a[1] = f2bf(x0.y); a[2] = f2bf(x0.z); a[3] = f2bf(x0.w);
        a[4] = f2bf(x1.x); a[5] = f2bf(x1.y); a[6] = f2bf(x1.z); a[7] = f2bf(x1.w);
        const short* bb = WFh + (size_t)((kt >> 3) + quad) * (D * 8) + li * 8;
        bf16x8 b0 = *(const bf16x8*)(bb);
        bf16x8 b1 = *(const bf16x8*)(bb + 128);
        bf16x8 b2 = *(const bf16x8*)(bb + 256);
        bf16x8 b3 = *(const bf16x8*)(bb + 384);
        c0 = __builtin_amdgcn_mfma_f32_16x16x32_bf16(a, b0, c0, 0, 0, 0);
        c1 = __builtin_amdgcn_mfma_f32_16x16x32_bf16(a, b1, c1, 0, 0, 0);
        c2 = __builtin_amdgcn_mfma_f32_16x16x32_bf16(a, b2, c2, 0, 0, 0);
        c3 = __builtin_amdgcn_mfma_f32_16x16x32_bf16(a, b3, c3, 0, 0, 0);
    }
    float av4[4], bv4[4];
    #pragma unroll
    for (int t4 = 0; t4 < 4; ++t4) {
        av4[t4] = av[h * D + t4 * 16 + li];
        bv4[t4] = bv[h * D + t4 * 16 + li];
    }
    float tiles[4][4];
    #pragma unroll
    for (int r = 0; r < 4; ++r) { tiles[0][r] = c0[r]; tiles[1][r] = c1[r]; tiles[2][r] = c2[r]; tiles[3][r] = c3[r]; }
    #pragma unroll
    for (int r = 0; r < 4; ++r) {
        const int row = i0 + w * 16 + quad * 4 + r;
        float pa = 0.f, pb = 0.f;
        #pragma unroll
        for (int t4 = 0; t4 < 4; ++t4) {
            const float v = tiles[t4][r];
            const int d = t4 * 16 + li;
            Out[((size_t)h * N_NODES + row) * D + d] = v;
            WBout[((size_t)h * (N_NODES / 8) + (row >> 3)) * (D * 8) + d * 8 + (row & 7)] = f2bf(v);
            pa += v * av4[t4];
            pb += v * bv4[t4];
        }
        #pragma unroll
        for (int off = 1; off < 16; off <<= 1) {
            pa += __shfl_xor(pa, off);
            pb += __shfl_xor(pb, off);
        }
        if (li == 0) {
            fs[(size_t)h * N_NODES + row] = pa;
            fd[(size_t)h * N_NODES + row] = pb;
        }
    }
}

// ---------------------------------------------------------------- fused stats: colmean (x<16) + gmax (x==16)
__global__ void k_stats(const float* __restrict__ fd, const float* __restrict__ Wh,
                        float* __restrict__ gmax, float* __restrict__ colmean) {
    const int h = blockIdx.y;
    const int t = threadIdx.x;
    __shared__ float cs[4][64];
    if (blockIdx.x == 16) {                    // global max of fd
        float m = -INFINITY;
        for (int i = t; i < N_NODES; i += 256) m = fmaxf(m, fd[(size_t)h * N_NODES + i]);
        #pragma unroll
        for (int off = 32; off > 0; off >>= 1) m = fmaxf(m, __shfl_xor(m, off));
        if ((t & 63) == 0) cs[t >> 6][0] = m;
        __syncthreads();
        if (t == 0)
            gmax[h] = fmaxf(fmaxf(cs[0][0], cs[1][0]), fmaxf(cs[2][0], cs[3][0]));
        return;
    }
    const int i0 = blockIdx.x * 256;
    const int d  = t & 63, rg = t >> 6;
    const float* __restrict__ base = Wh + (size_t)h * N_NODES * D;
    float s = 0.f;
    #pragma unroll 8
    for (int r = rg; r < 256; r += 4) s += base[(size_t)(i0 + r) * D + d];
    cs[rg][d] = s;
    __syncthreads();
    if (t < 64)
        atomicAdd(&colmean[h * D + t],
                  (cs[0][t] + cs[1][t] + cs[2][t] + cs[3][t]) * (1.f / (float)N_NODES));
}

// ---------------------------------------------------------------- exp precompute (factored softmax)
__global__ void k_prep(const float* __restrict__ fs, const float* __restrict__ fd,
                       const float* __restrict__ gmax,
                       float* __restrict__ Ppos, float* __restrict__ Pneg,
                       float* __restrict__ T, float* __restrict__ Ed,
                       float* __restrict__ Ed2) {
    const int h = blockIdx.y;
    const size_t o = (size_t)h * N_NODES + blockIdx.x * 256 + threadIdx.x;
    const float fsv = fs[o], fdv = fd[o], gm = gmax[h];
    const float em = fsv + gm;
    const float m  = fmaxf(em, 0.2f * em);
    Ppos[o] = __expf(fsv - m);
    Pneg[o] = __expf(0.2f * fsv - m);
    T[o]    = __expf(-fsv);
    Ed[o]   = __expf(fdv);
    Ed2[o]  = __expf(0.2f * fdv);
}

// ---------------------------------------------------------------- MFMA attention aggregation (j-split)
// m97-style: B-tile (128 j = 16 KB) async-DMA'd into LDS, double-buffered,
// one barrier per tile; shared by all 4 waves (4x VMEM cut vs r5).
__global__ void __launch_bounds__(256) k_accum(
    const unsigned int* __restrict__ bits32,
    const short* __restrict__ WB,
    const float* __restrict__ Pposb, const float* __restrict__ Pnegb,
    const float* __restrict__ Tb, const float* __restrict__ Edb,
    const float* __restrict__ Ed2b,
    float* __restrict__ num, float* __restrict__ den, int kslab) {

    __shared__ __align__(16) short Bt[2][16 * 64 * 8];   // 2 x 16 KB

    const int h = blockIdx.y, i0 = blockIdx.x * 64, slab = blockIdx.z;
    const int t = threadIdx.x, w = t >> 6, lane = t & 63;
    const int li = lane & 15, quad = lane >> 4, k0 = quad * 8;
    const int    i_row = i0 + w * 16 + li;
    const size_t ho    = (size_t)h * N_NODES;
    const float  Pp = Pposb[ho + i_row], Pn = Pnegb[ho + i_row], Tv = Tb[ho + i_row];
    const float* __restrict__ Ed = Edb + ho;
    const float* __restrict__ Eg = Ed2b + ho;
    const short* __restrict__ Bh = WB + (size_t)h * (N_NODES / 8) * D * 8;
    const unsigned int* __restrict__ brow = bits32 + (size_t)i_row * (NWORDS * 2);

    f32x4 c0 = {0.f, 0.f, 0.f, 0.f}, c1 = c0, c2 = c0, c3 = c0, c5 = c0;
    bf16x8 ones;
    #pragma unroll
    for (int j = 0; j < 8; ++j) ones[j] = (short)0x3F80;

    const int k_beg = slab * kslab;
    const int ntile = kslab / 128;

    // stage 16 KB tile: 256 threads x 4 x 16B DMA, lane-contiguous in LDS
    auto stage = [&](int buf, int jt) {
        const short* src = Bh + (size_t)(jt >> 3) * (D * 8);
        #pragma unroll
        for (int p = 0; p < 4; ++p)
            gl2lds16(src + (size_t)(p * 256 + t) * 8, &Bt[buf][(p * 256 + t) * 8]);
    };

    stage(0, k_beg);
    for (int tile = 0; tile < ntile; ++tile) {
        const int jt = k_beg + tile * 128;
        __syncthreads();                       // DMA for Bt[tile&1] drained; overwrite-safe
        if (tile + 1 < ntile) stage((tile + 1) & 1, jt + 128);
        const short* Bl = Bt[tile & 1];
        const uint4 bwv = *(const uint4*)&brow[jt >> 5];   // 128 adjacency bits for i_row
        const unsigned int bwa[4] = {bwv.x, bwv.y, bwv.z, bwv.w};
        #pragma unroll
        for (int s = 0; s < 4; ++s) {
            const int kt = jt + s * 32;
            const float4 e0 = *(const float4*)&Ed[kt + k0];
            const float4 e1 = *(const float4*)&Ed[kt + k0 + 4];
            const float4 g0 = *(const float4*)&Eg[kt + k0];
            const float4 g1 = *(const float4*)&Eg[kt + k0 + 4];
            const unsigned int byt = (bwa[s] >> k0) & 0xFFu;
            float ev[8], gv[8];
            ev[0] = e0.x; ev[1] = e0.y; ev[2] = e0.z; ev[3] = e0.w;
            ev[4] = e1.x; ev[5] = e1.y; ev[6] = e1.z; ev[7] = e1.w;
            gv[0] = g0.x; gv[1] = g0.y; gv[2] = g0.z; gv[3] = g0.w;
            gv[4] = g1.x; gv[5] = g1.y; gv[6] = g1.z; gv[7] = g1.w;
            unsigned int pa[8];
            #pragma unroll
            for (int j = 0; j < 8; ++j) {
                const bool pos = ev[j] > Tv;           // <=> fs_i + fd_j > 0
                const float val = pos ? ev[j] : gv[j];
                const float fac = pos ? Pp : Pn;
                const float p   = val * fac;
                const int   msk = ((int)(byt << (31 - j))) >> 31;
                pa[j] = __builtin_bit_cast(unsigned int, p) & (unsigned int)msk;
            }
            bf16x8 a;
            unsigned int* au = (unsigned int*)&a;
            au[0] = __builtin_amdgcn_perm(pa[1], pa[0], 0x07060302);
            au[1] = __builtin_amdgcn_perm(pa[3], pa[2], 0x07060302);
            au[2] = __builtin_amdgcn_perm(pa[5], pa[4], 0x07060302);
            au[3] = __builtin_amdgcn_perm(pa[7], pa[6], 0x07060302);

            const short* bb = Bl + (size_t)((s * 4 + quad) * 64 + li) * 8;
            bf16x8 b0 = *(const bf16x8*)(bb);
            bf16x8 b1 = *(const bf16x8*)(bb + 128);
            bf16x8 b2 = *(const bf16x8*)(bb + 256);
            bf16x8 b3 = *(const bf16x8*)(bb + 384);
            c0 = __builtin_amdgcn_mfma_f32_16x16x32_bf16(a, b0, c0, 0, 0, 0);
            c1 = __builtin_amdgcn_mfma_f32_16x16x32_bf16(a, b1, c1, 0, 0, 0);
            c2 = __builtin_amdgcn_mfma_f32_16x16x32_bf16(a, b2, c2, 0, 0, 0);
            c3 = __builtin_amdgcn_mfma_f32_16x16x32_bf16(a, b3, c3, 0, 0, 0);
            c5 = __builtin_amdgcn_mfma_f32_16x16x32_bf16(a, ones, c5, 0, 0, 0);
        }
    }

    const size_t so = (size_t)(slab * gridDim.y + h);
    float tiles[4][4];
    #pragma unroll
    for (int r = 0; r < 4; ++r) { tiles[0][r] = c0[r]; tiles[1][r] = c1[r]; tiles[2][r] = c2[r]; tiles[3][r] = c3[r]; }
    #pragma unroll
    for (int t4 = 0; t4 < 4; ++t4)
        #pragma unroll
        for (int r = 0; r < 4; ++r) {
            const int row = i0 + w * 16 + quad * 4 + r;
            num[(so * N_NODES + row) * D + t4 * 16 + li] = tiles[t4][r];
        }
    if (li == 0)
        #pragma unroll
        for (int r = 0; r < 4; ++r)
            den[so * N_NODES + i0 + w * 16 + quad * 4 + r] = c5[r];
}

// ---------------------------------------------------------------- layer-1 combine (JS=2): norm+fallback+ELU
__global__ void k_post1(const float* __restrict__ num, const float* __restrict__ den,
                        const float* __restrict__ colmean, float* __restrict__ hcat) {
    const int h   = blockIdx.y;
    const int i0  = blockIdx.x * 64;
    const int t   = threadIdx.x;
    const int row = i0 + (t >> 2);
    const int cb  = (t & 3) * 16;
    const size_t HN = (size_t)gridDim.y * N_NODES;
    const size_t r0 = (size_t)h * N_NODES + row;
    const float dsum = den[r0] + den[HN + r0];
    const bool  uni  = !(dsum > 0.f);
    const float linv = uni ? 0.f : 1.f / dsum;
    #pragma unroll
    for (int c = 0; c < 4; ++c) {
        const int col = cb + c * 4;
        float4 a = *(const float4*)&num[r0 * D + col];
        float4 b = *(const float4*)&num[(HN + r0) * D + col];
        float4 v;
        v.x = (a.x + b.x) * linv; v.y = (a.y + b.y) * linv;
        v.z = (a.z + b.z) * linv; v.w = (a.w + b.w) * linv;
        if (uni) v = *(const float4*)&colmean[h * D + col];
        v.x = v.x > 0.f ? v.x : __expf(v.x) - 1.f;
        v.y = v.y > 0.f ? v.y : __expf(v.y) - 1.f;
        v.z = v.z > 0.f ? v.z : __expf(v.z) - 1.f;
        v.w = v.w > 0.f ? v.w : __expf(v.w) - 1.f;
        *(float4*)&hcat[(size_t)row * (H * D) + h * D + col] = v;
    }
}

// ---------------------------------------------------------------- layer-2 combine (JS=8) + ELU + log_softmax
__global__ void k_lsm(const float* __restrict__ num, const float* __restrict__ den,
                      const float* __restrict__ cm, float* __restrict__ out) {
    const int n    = blockIdx.x * 4 + (threadIdx.x >> 6);
    const int lane = threadIdx.x & 63;
    float v = 0.f, ds = 0.f;
    #pragma unroll
    for (int s = 0; s < 8; ++s) v  += num[((size_t)s * N_NODES + n) * D + lane];
    #pragma unroll
    for (int s = 0; s < 8; ++s) ds += den[(size_t)s * N_NODES + n];
    v = (ds > 0.f) ? v / ds : cm[lane];
    v = v > 0.f ? v : __expf(v) - 1.f;
    float mx = v;
    #pragma unroll
    for (int off = 32; off > 0; off >>= 1) mx = fmaxf(mx, __shfl_xor(mx, off));
    float ex = __expf(v - mx);
    float sum = ex;
    #pragma unroll
    for (int off = 32; off > 0; off >>= 1) sum += __shfl_xor(sum, off);
    out[(size_t)n * D + lane] = (v - mx) - __logf(sum);
}

// ----------------------------------------------------------------
extern "C" void kernel_launch(void* const* d_in, const int* in_sizes, int n_in,
                              void* d_out, int out_size, void* d_ws, size_t ws_size,
                              hipStream_t stream) {
    const float* x      = (const float*)d_in[0];
    const int*   adj    = (const int*)d_in[1];
    const float* W      = (const float*)d_in[2];
    const float* a_src  = (const float*)d_in[3];
    const float* a_dst  = (const float*)d_in[4];
    const float* W_o    = (const float*)d_in[5];
    const float* ao_src = (const float*)d_in[6];
    const float* ao_dst = (const float*)d_in[7];
    float* out = (float*)d_out;

    char* wsp = (char*)d_ws;
    size_t off = 0;
    auto alloc = [&](size_t bytes) -> void* {
        void* p = wsp + off;
        off += (bytes + 255) & ~(size_t)255;
        return p;
    };
    unsigned long long* adj_bits = (unsigned long long*)alloc((size_t)N_NODES * NWORDS * 8);
    short* WF1   = (short*)alloc((size_t)H * 64 * D * 8 * 2);
    short* WoF   = (short*)alloc((size_t)64 * D * 8 * 2);
    float* Wh    = (float*)alloc((size_t)H * N_NODES * D * 4);
    short* WhB   = (short*)alloc((size_t)H * N_NODES * D * 2);
    float* fs1   = (float*)alloc((size_t)H * N_NODES * 4);
    float* fd1   = (float*)alloc((size_t)H * N_NODES * 4);
    float* gmax1 = (float*)alloc((size_t)H * 4);
    float* cm1   = (float*)alloc((size_t)H * D * 4);
    float* Pp1   = (float*)alloc((size_t)H * N_NODES * 4);
    float* Pn1   = (float*)alloc((size_t)H * N_NODES * 4);
    float* T1    = (float*)alloc((size_t)H * N_NODES * 4);
    float* Ed1   = (float*)alloc((size_t)H * N_NODES * 4);
    float* Ee1   = (float*)alloc((size_t)H * N_NODES * 4);
    float* num1  = (float*)alloc((size_t)2 * H * N_NODES * D * 4);
    float* den1  = (float*)alloc((size_t)2 * H * N_NODES * 4);
    float* hcat  = (float*)alloc((size_t)N_NODES * H * D * 4);
    float* Who   = (float*)alloc((size_t)N_NODES * D * 4);
    short* WhoB  = (short*)alloc((size_t)N_NODES * D * 2);
    float* fs2   = (float*)alloc((size_t)N_NODES * 4);
    float* fd2   = (float*)alloc((size_t)N_NODES * 4);
    float* gmax2 = (float*)alloc(4);
    float* cm2   = (float*)alloc((size_t)D * 4);
    float* Pp2   = (float*)alloc((size_t)N_NODES * 4);
    float* Pn2   = (float*)alloc((size_t)N_NODES * 4);
    float* T2    = (float*)alloc((size_t)N_NODES * 4);
    float* Ed2   = (float*)alloc((size_t)N_NODES * 4);
    float* Ee2   = (float*)alloc((size_t)N_NODES * 4);
    float* num2  = (float*)alloc((size_t)8 * N_NODES * D * 4);
    float* den2  = (float*)alloc((size_t)8 * N_NODES * 4);

    const unsigned int* bits32 = (const unsigned int*)adj_bits;

    hipMemsetAsync(cm1, 0, (size_t)H * D * 4, stream);
    hipMemsetAsync(cm2, 0, (size_t)D * 4, stream);

    k_bits <<<dim3(N_NODES * N_NODES / 256), dim3(256), 0, stream>>>(adj, adj_bits);
    k_wfrag<<<dim3(H * FDIM * D / 256), dim3(256), 0, stream>>>(W, WF1);
    k_wfrag<<<dim3(FDIM * D / 256), dim3(256), 0, stream>>>(W_o, WoF);

    // layer 1 (8 heads, concat + ELU)
    k_gemm <<<dim3(N_NODES / 64, H), dim3(256), 0, stream>>>(x, WF1, a_src, a_dst,
                                                             Wh, WhB, fs1, fd1);
    k_stats<<<dim3(17, H), dim3(256), 0, stream>>>(fd1, Wh, gmax1, cm1);
    k_prep <<<dim3(N_NODES / 256, H), dim3(256), 0, stream>>>(fs1, fd1, gmax1, Pp1, Pn1, T1, Ed1, Ee1);
    k_accum<<<dim3(N_NODES / 64, H, 2), dim3(256), 0, stream>>>(bits32, WhB, Pp1, Pn1, T1, Ed1, Ee1,
                                                                num1, den1, N_NODES / 2);
    k_post1<<<dim3(N_NODES / 64, H), dim3(256), 0, stream>>>(num1, den1, cm1, hcat);

    // layer 2 (single output head)
    k_gemm <<<dim3(N_NODES / 64, 1), dim3(256), 0, stream>>>(hcat, WoF, ao_src, ao_dst,
                                                             Who, WhoB, fs2, fd2);
    k_stats<<<dim3(17, 1), dim3(256), 0, stream>>>(fd2, Who, gmax2, cm2);
    k_prep <<<dim3(N_NODES / 256, 1), dim3(256), 0, stream>>>(fs2, fd2, gmax2, Pp2, Pn2, T2, Ed2, Ee2);
    k_accum<<<dim3(N_NODES / 64, 1, 8), dim3(256), 0, stream>>>(bits32, WhoB, Pp2, Pn2, T2, Ed2, Ee2,
                                                                num2, den2, N_NODES / 8);
    k_lsm  <<<dim3(N_NODES / 4), dim3(256), 0, stream>>>(num2, den2, cm2, out);
}

// Round 7
// 227.176 us; speedup vs baseline: 1.6531x; 1.1238x over previous
//
#include <hip/hip_runtime.h>
#include <hip/hip_bf16.h>
#include <math.h>

#define N_NODES 4096
#define FDIM 512            // K of both GEMMs (F_in = H*D = 512)
#define D 64
#define H 8
#define NWORDS (N_NODES / 64)

typedef __attribute__((ext_vector_type(8))) short bf16x8;   // 8 bf16 = 4 VGPRs
typedef __attribute__((ext_vector_type(4))) float f32x4;

__device__ inline short f2bf(float x) {                     // RNE
    return (short)((__builtin_bit_cast(unsigned int, x) + 0x8000u) >> 16);
}

__device__ inline int sext_bit(unsigned int v, int j) {     // all-ones iff bit j set
#if defined(__has_builtin) && __has_builtin(__builtin_amdgcn_sbfe)
    return __builtin_amdgcn_sbfe((int)v, j, 1);
#else
    return ((int)(v << (31 - j))) >> 31;
#endif
}

// async global->LDS 16B copy (DMA). LDS dst must be wave-uniform base + lane*16.
__device__ inline void gl2lds16(const void* g, void* l) {
#if defined(__has_builtin) && __has_builtin(__builtin_amdgcn_global_load_lds)
    __builtin_amdgcn_global_load_lds(
        (const __attribute__((address_space(1))) unsigned int*)g,
        (__attribute__((address_space(3))) unsigned int*)l, 16, 0, 0);
#else
    *(uint4*)l = *(const uint4*)g;
#endif
}

// ---------------------------------------------------------------- adj -> bitmask
__global__ void k_bits(const int* __restrict__ adj, unsigned long long* __restrict__ bits) {
    int idx = blockIdx.x * 256 + threadIdx.x;
    unsigned long long m = __ballot(adj[idx] != 0);
    if ((threadIdx.x & 63) == 0) bits[idx >> 6] = m;
}

// ---------------------------------------------------------------- W [Hn,512,64] fp32 -> B-frag bf16
__global__ void k_wfrag(const float* __restrict__ Wsrc, short* __restrict__ WF) {
    const size_t idx = (size_t)blockIdx.x * 256 + threadIdx.x;   // (h*512+k)*64+d
    const int d = idx & 63;
    const int k = (int)(idx >> 6) & 511;
    const int h = (int)(idx >> 15);
    WF[(((size_t)h * 64 + (k >> 3)) * 64 + d) * 8 + (k & 7)] = f2bf(Wsrc[idx]);
}

// ---------------------------------------------------------------- MFMA GEMM [N,512]@[512,64] per head
// Also writes bf16 frag copy of C and fused fs/fd = C.av / C.bv row dot-products.
__global__ void __launch_bounds__(256) k_gemm(
    const float* __restrict__ X, const short* __restrict__ WF,
    const float* __restrict__ av, const float* __restrict__ bv,
    float* __restrict__ Out, short* __restrict__ WBout,
    float* __restrict__ fs, float* __restrict__ fd) {
    const int h  = blockIdx.y;
    const int i0 = blockIdx.x * 64;
    const int t = threadIdx.x, w = t >> 6, lane = t & 63;
    const int li = lane & 15, quad = lane >> 4, k0 = quad * 8;
    const int row_a = i0 + w * 16 + li;
    const float* __restrict__ Xr  = X + (size_t)row_a * FDIM;
    const short* __restrict__ WFh = WF + (size_t)h * 64 * D * 8;

    f32x4 c0 = {0.f, 0.f, 0.f, 0.f}, c1 = c0, c2 = c0, c3 = c0;
    #pragma unroll 4
    for (int kt = 0; kt < FDIM; kt += 32) {
        float4 x0 = *(const float4*)&Xr[kt + k0];
        float4 x1 = *(const float4*)&Xr[kt + k0 + 4];
        bf16x8 a;
        a[0] = f2bf(x0.x); a[1] = f2bf(x0.y); a[2] = f2bf(x0.z); a[3] = f2bf(x0.w);
        a[4] = f2bf(x1.x); a[5] = f2bf(x1.y); a[6] = f2bf(x1.z); a[7] = f2bf(x1.w);
        const short* bb = WFh + (size_t)((kt >> 3) + quad) * (D * 8) + li * 8;
        bf16x8 b0 = *(const bf16x8*)(bb);
        bf16x8 b1 = *(const bf16x8*)(bb + 128);
        bf16x8 b2 = *(const bf16x8*)(bb + 256);
        bf16x8 b3 = *(const bf16x8*)(bb + 384);
        c0 = __builtin_amdgcn_mfma_f32_16x16x32_bf16(a, b0, c0, 0, 0, 0);
        c1 = __builtin_amdgcn_mfma_f32_16x16x32_bf16(a, b1, c1, 0, 0, 0);
        c2 = __builtin_amdgcn_mfma_f32_16x16x32_bf16(a, b2, c2, 0, 0, 0);
        c3 = __builtin_amdgcn_mfma_f32_16x16x32_bf16(a, b3, c3, 0, 0, 0);
    }
    float av4[4], bv4[4];
    #pragma unroll
    for (int t4 = 0; t4 < 4; ++t4) {
        av4[t4] = av[h * D + t4 * 16 + li];
        bv4[t4] = bv[h * D + t4 * 16 + li];
    }
    float tiles[4][4];
    #pragma unroll
    for (int r = 0; r < 4; ++r) { tiles[0][r] = c0[r]; tiles[1][r] = c1[r]; tiles[2][r] = c2[r]; tiles[3][r] = c3[r]; }
    #pragma unroll
    for (int r = 0; r < 4; ++r) {
        const int row = i0 + w * 16 + quad * 4 + r;
        float pa = 0.f, pb = 0.f;
        #pragma unroll
        for (int t4 = 0; t4 < 4; ++t4) {
            const float v = tiles[t4][r];
            const int d = t4 * 16 + li;
            Out[((size_t)h * N_NODES + row) * D + d] = v;
            WBout[((size_t)h * (N_NODES / 8) + (row >> 3)) * (D * 8) + d * 8 + (row & 7)] = f2bf(v);
            pa += v * av4[t4];
            pb += v * bv4[t4];
        }
        #pragma unroll
        for (int off = 1; off < 16; off <<= 1) {
            pa += __shfl_xor(pa, off);
            pb += __shfl_xor(pb, off);
        }
        if (li == 0) {
            fs[(size_t)h * N_NODES + row] = pa;
            fd[(size_t)h * N_NODES + row] = pb;
        }
    }
}

// ---------------------------------------------------------------- fused stats: colmean (x<16) + gmax (x==16)
__global__ void k_stats(const float* __restrict__ fd, const float* __restrict__ Wh,
                        float* __restrict__ gmax, float* __restrict__ colmean) {
    const int h = blockIdx.y;
    const int t = threadIdx.x;
    __shared__ float cs[4][64];
    if (blockIdx.x == 16) {                    // global max of fd
        float m = -INFINITY;
        for (int i = t; i < N_NODES; i += 256) m = fmaxf(m, fd[(size_t)h * N_NODES + i]);
        #pragma unroll
        for (int off = 32; off > 0; off >>= 1) m = fmaxf(m, __shfl_xor(m, off));
        if ((t & 63) == 0) cs[t >> 6][0] = m;
        __syncthreads();
        if (t == 0)
            gmax[h] = fmaxf(fmaxf(cs[0][0], cs[1][0]), fmaxf(cs[2][0], cs[3][0]));
        return;
    }
    const int i0 = blockIdx.x * 256;
    const int d  = t & 63, rg = t >> 6;
    const float* __restrict__ base = Wh + (size_t)h * N_NODES * D;
    float s = 0.f;
    #pragma unroll 8
    for (int r = rg; r < 256; r += 4) s += base[(size_t)(i0 + r) * D + d];
    cs[rg][d] = s;
    __syncthreads();
    if (t < 64)
        atomicAdd(&colmean[h * D + t],
                  (cs[0][t] + cs[1][t] + cs[2][t] + cs[3][t]) * (1.f / (float)N_NODES));
}

// ---------------------------------------------------------------- exp precompute (factored softmax, max-identity)
// p_ij ∝ max(Ed_j, Eg_j * R_i) with a positive per-row factor that cancels in
// num/den normalization.  Ed=e^{fd-gm}, Eg=e^{0.2(fd-gm)}, R=e^{-0.8(fs+gm)}.
__global__ void k_prep(const float* __restrict__ fs, const float* __restrict__ fd,
                       const float* __restrict__ gmax,
                       float* __restrict__ Rout, float* __restrict__ Ed,
                       float* __restrict__ Eg) {
    const int h = blockIdx.y;
    const size_t o = (size_t)h * N_NODES + blockIdx.x * 256 + threadIdx.x;
    const float fsv = fs[o], fdv = fd[o], gm = gmax[h];
    Rout[o] = __expf(-0.8f * (fsv + gm));
    Ed[o]   = __expf(fdv - gm);
    Eg[o]   = __expf(0.2f * (fdv - gm));
}

// ---------------------------------------------------------------- MFMA attention aggregation (j-split)
// B-tile (128 j = 16 KB) + Ed/Eg (1 KB) async-DMA'd into LDS, double-buffered.
// Inner: p = max(Ed_j, Eg_j*R_i) masked via sbfe+and; packed to bf16 A-frags.
__global__ void __launch_bounds__(256) k_accum(
    const unsigned int* __restrict__ bits32,
    const short* __restrict__ WB,
    const float* __restrict__ Rb, const float* __restrict__ Edb,
    const float* __restrict__ Egb,
    float* __restrict__ num, float* __restrict__ den, int kslab) {

    __shared__ __align__(16) short Bt[2][16 * 64 * 8];   // 2 x 16 KB
    __shared__ __align__(16) float EG[2][256];           // per buf: e[0..127], g[0..127]

    const int h = blockIdx.y, i0 = blockIdx.x * 64, slab = blockIdx.z;
    const int t = threadIdx.x, w = t >> 6, lane = t & 63;
    const int li = lane & 15, quad = lane >> 4, k0 = quad * 8;
    const int    i_row = i0 + w * 16 + li;
    const size_t ho    = (size_t)h * N_NODES;
    const float  Rv    = Rb[ho + i_row];
    const float* __restrict__ Ed = Edb + ho;
    const float* __restrict__ Eg = Egb + ho;
    const short* __restrict__ Bh = WB + (size_t)h * (N_NODES / 8) * D * 8;
    const unsigned int* __restrict__ brow = bits32 + (size_t)i_row * (NWORDS * 2);

    f32x4 c0 = {0.f, 0.f, 0.f, 0.f}, c1 = c0, c2 = c0, c3 = c0, c5 = c0;
    bf16x8 ones;
    #pragma unroll
    for (int j = 0; j < 8; ++j) ones[j] = (short)0x3F80;

    const int k_beg = slab * kslab;
    const int ntile = kslab / 128;

    // stage 16 KB B-tile + 1 KB e/g: 256 threads x 4 x 16B, wave0 lanes stage e|g
    auto stage = [&](int buf, int jt) {
        const short* src = Bh + (size_t)(jt >> 3) * (D * 8);
        #pragma unroll
        for (int p = 0; p < 4; ++p)
            gl2lds16(src + (size_t)(p * 256 + t) * 8, &Bt[buf][(p * 256 + t) * 8]);
        if (w == 0) {
            const float* egsrc = (lane < 32) ? &Ed[jt + lane * 4]
                                             : &Eg[jt + (lane - 32) * 4];
            gl2lds16(egsrc, &EG[buf][lane * 4]);
        }
    };

    stage(0, k_beg);
    uint4 bwv = *(const uint4*)&brow[k_beg >> 5];       // 128 adjacency bits, prefetched
    for (int tile = 0; tile < ntile; ++tile) {
        const int jt = k_beg + tile * 128;
        __syncthreads();                                // DMA for Bt[tile&1] drained
        if (tile + 1 < ntile) stage((tile + 1) & 1, jt + 128);
        const short* Bl  = Bt[tile & 1];
        const float* EGl = EG[tile & 1];
        const unsigned int bwa[4] = {bwv.x, bwv.y, bwv.z, bwv.w};
        if (tile + 1 < ntile) bwv = *(const uint4*)&brow[(jt + 128) >> 5];
        #pragma unroll
        for (int s = 0; s < 4; ++s) {
            const float4 e0 = *(const float4*)&EGl[s * 32 + k0];
            const float4 e1 = *(const float4*)&EGl[s * 32 + k0 + 4];
            const float4 g0 = *(const float4*)&EGl[128 + s * 32 + k0];
            const float4 g1 = *(const float4*)&EGl[128 + s * 32 + k0 + 4];
            const unsigned int byt = (bwa[s] >> k0) & 0xFFu;
            float ev[8], gv[8];
            ev[0] = e0.x; ev[1] = e0.y; ev[2] = e0.z; ev[3] = e0.w;
            ev[4] = e1.x; ev[5] = e1.y; ev[6] = e1.z; ev[7] = e1.w;
            gv[0] = g0.x; gv[1] = g0.y; gv[2] = g0.z; gv[3] = g0.w;
            gv[4] = g1.x; gv[5] = g1.y; gv[6] = g1.z; gv[7] = g1.w;
            unsigned int pa[8];
            #pragma unroll
            for (int j = 0; j < 8; ++j) {
                const float p = fmaxf(ev[j], gv[j] * Rv);   // == leaky branch select
                pa[j] = __builtin_bit_cast(unsigned int, p)
                        & (unsigned int)sext_bit(byt, j);
            }
            bf16x8 a;
            unsigned int* au = (unsigned int*)&a;
            au[0] = __builtin_amdgcn_perm(pa[1], pa[0], 0x07060302);
            au[1] = __builtin_amdgcn_perm(pa[3], pa[2], 0x07060302);
            au[2] = __builtin_amdgcn_perm(pa[5], pa[4], 0x07060302);
            au[3] = __builtin_amdgcn_perm(pa[7], pa[6], 0x07060302);

            const short* bb = Bl + (size_t)((s * 4 + quad) * 64 + li) * 8;
            bf16x8 b0 = *(const bf16x8*)(bb);
            bf16x8 b1 = *(const bf16x8*)(bb + 128);
            bf16x8 b2 = *(const bf16x8*)(bb + 256);
            bf16x8 b3 = *(const bf16x8*)(bb + 384);
            c0 = __builtin_amdgcn_mfma_f32_16x16x32_bf16(a, b0, c0, 0, 0, 0);
            c1 = __builtin_amdgcn_mfma_f32_16x16x32_bf16(a, b1, c1, 0, 0, 0);
            c2 = __builtin_amdgcn_mfma_f32_16x16x32_bf16(a, b2, c2, 0, 0, 0);
            c3 = __builtin_amdgcn_mfma_f32_16x16x32_bf16(a, b3, c3, 0, 0, 0);
            c5 = __builtin_amdgcn_mfma_f32_16x16x32_bf16(a, ones, c5, 0, 0, 0);
        }
    }

    const size_t so = (size_t)(slab * gridDim.y + h);
    float tiles[4][4];
    #pragma unroll
    for (int r = 0; r < 4; ++r) { tiles[0][r] = c0[r]; tiles[1][r] = c1[r]; tiles[2][r] = c2[r]; tiles[3][r] = c3[r]; }
    #pragma unroll
    for (int t4 = 0; t4 < 4; ++t4)
        #pragma unroll
        for (int r = 0; r < 4; ++r) {
            const int row = i0 + w * 16 + quad * 4 + r;
            num[(so * N_NODES + row) * D + t4 * 16 + li] = tiles[t4][r];
        }
    if (li == 0)
        #pragma unroll
        for (int r = 0; r < 4; ++r)
            den[so * N_NODES + i0 + w * 16 + quad * 4 + r] = c5[r];
}

// ---------------------------------------------------------------- layer-1 combine (JS=2): norm+fallback+ELU
__global__ void k_post1(const float* __restrict__ num, const float* __restrict__ den,
                        const float* __restrict__ colmean, float* __restrict__ hcat) {
    const int h   = blockIdx.y;
    const int i0  = blockIdx.x * 64;
    const int t   = threadIdx.x;
    const int row = i0 + (t >> 2);
    const int cb  = (t & 3) * 16;
    const size_t HN = (size_t)gridDim.y * N_NODES;
    const size_t r0 = (size_t)h * N_NODES + row;
    const float dsum = den[r0] + den[HN + r0];
    const bool  uni  = !(dsum > 0.f);
    const float linv = uni ? 0.f : 1.f / dsum;
    #pragma unroll
    for (int c = 0; c < 4; ++c) {
        const int col = cb + c * 4;
        float4 a = *(const float4*)&num[r0 * D + col];
        float4 b = *(const float4*)&num[(HN + r0) * D + col];
        float4 v;
        v.x = (a.x + b.x) * linv; v.y = (a.y + b.y) * linv;
        v.z = (a.z + b.z) * linv; v.w = (a.w + b.w) * linv;
        if (uni) v = *(const float4*)&colmean[h * D + col];
        v.x = v.x > 0.f ? v.x : __expf(v.x) - 1.f;
        v.y = v.y > 0.f ? v.y : __expf(v.y) - 1.f;
        v.z = v.z > 0.f ? v.z : __expf(v.z) - 1.f;
        v.w = v.w > 0.f ? v.w : __expf(v.w) - 1.f;
        *(float4*)&hcat[(size_t)row * (H * D) + h * D + col] = v;
    }
}

// ---------------------------------------------------------------- layer-2 combine (JS=8) + ELU + log_softmax
__global__ void k_lsm(const float* __restrict__ num, const float* __restrict__ den,
                      const float* __restrict__ cm, float* __restrict__ out) {
    const int n    = blockIdx.x * 4 + (threadIdx.x >> 6);
    const int lane = threadIdx.x & 63;
    float v = 0.f, ds = 0.f;
    #pragma unroll
    for (int s = 0; s < 8; ++s) v  += num[((size_t)s * N_NODES + n) * D + lane];
    #pragma unroll
    for (int s = 0; s < 8; ++s) ds += den[(size_t)s * N_NODES + n];
    v = (ds > 0.f) ? v / ds : cm[lane];
    v = v > 0.f ? v : __expf(v) - 1.f;
    float mx = v;
    #pragma unroll
    for (int off = 32; off > 0; off >>= 1) mx = fmaxf(mx, __shfl_xor(mx, off));
    float ex = __expf(v - mx);
    float sum = ex;
    #pragma unroll
    for (int off = 32; off > 0; off >>= 1) sum += __shfl_xor(sum, off);
    out[(size_t)n * D + lane] = (v - mx) - __logf(sum);
}

// ----------------------------------------------------------------
extern "C" void kernel_launch(void* const* d_in, const int* in_sizes, int n_in,
                              void* d_out, int out_size, void* d_ws, size_t ws_size,
                              hipStream_t stream) {
    const float* x      = (const float*)d_in[0];
    const int*   adj    = (const int*)d_in[1];
    const float* W      = (const float*)d_in[2];
    const float* a_src  = (const float*)d_in[3];
    const float* a_dst  = (const float*)d_in[4];
    const float* W_o    = (const float*)d_in[5];
    const float* ao_src = (const float*)d_in[6];
    const float* ao_dst = (const float*)d_in[7];
    float* out = (float*)d_out;

    char* wsp = (char*)d_ws;
    size_t off = 0;
    auto alloc = [&](size_t bytes) -> void* {
        void* p = wsp + off;
        off += (bytes + 255) & ~(size_t)255;
        return p;
    };
    unsigned long long* adj_bits = (unsigned long long*)alloc((size_t)N_NODES * NWORDS * 8);
    short* WF1   = (short*)alloc((size_t)H * 64 * D * 8 * 2);
    short* WoF   = (short*)alloc((size_t)64 * D * 8 * 2);
    float* Wh    = (float*)alloc((size_t)H * N_NODES * D * 4);
    short* WhB   = (short*)alloc((size_t)H * N_NODES * D * 2);
    float* fs1   = (float*)alloc((size_t)H * N_NODES * 4);
    float* fd1   = (float*)alloc((size_t)H * N_NODES * 4);
    float* gmax1 = (float*)alloc((size_t)H * 4);
    float* cm1   = (float*)alloc((size_t)H * D * 4);
    float* R1    = (float*)alloc((size_t)H * N_NODES * 4);
    float* Ed1   = (float*)alloc((size_t)H * N_NODES * 4);
    float* Ee1   = (float*)alloc((size_t)H * N_NODES * 4);
    float* num1  = (float*)alloc((size_t)2 * H * N_NODES * D * 4);
    float* den1  = (float*)alloc((size_t)2 * H * N_NODES * 4);
    float* hcat  = (float*)alloc((size_t)N_NODES * H * D * 4);
    float* Who   = (float*)alloc((size_t)N_NODES * D * 4);
    short* WhoB  = (short*)alloc((size_t)N_NODES * D * 2);
    float* fs2   = (float*)alloc((size_t)N_NODES * 4);
    float* fd2   = (float*)alloc((size_t)N_NODES * 4);
    float* gmax2 = (float*)alloc(4);
    float* cm2   = (float*)alloc((size_t)D * 4);
    float* R2    = (float*)alloc((size_t)N_NODES * 4);
    float* Ed2   = (float*)alloc((size_t)N_NODES * 4);
    float* Ee2   = (float*)alloc((size_t)N_NODES * 4);
    float* num2  = (float*)alloc((size_t)8 * N_NODES * D * 4);
    float* den2  = (float*)alloc((size_t)8 * N_NODES * 4);

    const unsigned int* bits32 = (const unsigned int*)adj_bits;

    hipMemsetAsync(cm1, 0, (size_t)H * D * 4, stream);
    hipMemsetAsync(cm2, 0, (size_t)D * 4, stream);

    k_bits <<<dim3(N_NODES * N_NODES / 256), dim3(256), 0, stream>>>(adj, adj_bits);
    k_wfrag<<<dim3(H * FDIM * D / 256), dim3(256), 0, stream>>>(W, WF1);
    k_wfrag<<<dim3(FDIM * D / 256), dim3(256), 0, stream>>>(W_o, WoF);

    // layer 1 (8 heads, concat + ELU)
    k_gemm <<<dim3(N_NODES / 64, H), dim3(256), 0, stream>>>(x, WF1, a_src, a_dst,
                                                             Wh, WhB, fs1, fd1);
    k_stats<<<dim3(17, H), dim3(256), 0, stream>>>(fd1, Wh, gmax1, cm1);
    k_prep <<<dim3(N_NODES / 256, H), dim3(256), 0, stream>>>(fs1, fd1, gmax1, R1, Ed1, Ee1);
    k_accum<<<dim3(N_NODES / 64, H, 2), dim3(256), 0, stream>>>(bits32, WhB, R1, Ed1, Ee1,
                                                                num1, den1, N_NODES / 2);
    k_post1<<<dim3(N_NODES / 64, H), dim3(256), 0, stream>>>(num1, den1, cm1, hcat);

    // layer 2 (single output head)
    k_gemm <<<dim3(N_NODES / 64, 1), dim3(256), 0, stream>>>(hcat, WoF, ao_src, ao_dst,
                                                             Who, WhoB, fs2, fd2);
    k_stats<<<dim3(17, 1), dim3(256), 0, stream>>>(fd2, Who, gmax2, cm2);
    k_prep <<<dim3(N_NODES / 256, 1), dim3(256), 0, stream>>>(fs2, fd2, gmax2, R2, Ed2, Ee2);
    k_accum<<<dim3(N_NODES / 64, 1, 8), dim3(256), 0, stream>>>(bits32, WhoB, R2, Ed2, Ee2,
                                                                num2, den2, N_NODES / 8);
    k_lsm  <<<dim3(N_NODES / 4), dim3(256), 0, stream>>>(num2, den2, cm2, out);
}